// Round 1
// baseline (4454.525 us; speedup 1.0000x reference)
//
#include <hip/hip_runtime.h>

// TsRnn: 2-layer LSTM scan, T=512 obs + 64 future steps, B=4096, CELL=100, fp32.
// Persistent kernel: 256 blocks x 512 threads; block owns 16 batch elements and
// runs all 576 steps. W_hh1 staged in LDS (k<92) + registers (k>=92).

#define TT     512
#define BATCH  4096
#define CELL   100
#define FUTS   64
#define KS     92            // k-range of W_hh1 staged in LDS
#define KR     8             // k-range in registers (KS+KR == CELL)
#define THREADS 512
#define BLOCKS  256
#define BPB    16            // batches per block
#define NB     4             // batches per thread
#define HROW   20            // padded h_lds row (floats) -> conflict-free writes

#define WLDS_FLOATS (KS * 4 * CELL)                     // 36800
#define SMEM_FLOATS (WLDS_FLOATS + CELL*HROW + BPB*CELL + 4*CELL + BPB + BPB)
#define SMEM_BYTES  (SMEM_FLOATS * 4)                   // 163328 <= 163840

static_assert(SMEM_BYTES <= 163840, "LDS overflow");

__device__ __forceinline__ float sigf(float x) {
  // 1/(1+e^-x); safe at +-inf: exp->inf => 0, exp->0 => 1
  return __fdividef(1.f, 1.f + __expf(-x));
}
__device__ __forceinline__ float tanhfast(float x) {
  // 1 - 2/(e^{2x}+1); safe at +-inf
  return 1.f - __fdividef(2.f, __expf(2.f * x) + 1.f);
}

#define FMA16(w4, h4)                                                          \
  acc[0][0] += (w4).x*(h4).x; acc[0][1] += (w4).x*(h4).y;                      \
  acc[0][2] += (w4).x*(h4).z; acc[0][3] += (w4).x*(h4).w;                      \
  acc[1][0] += (w4).y*(h4).x; acc[1][1] += (w4).y*(h4).y;                      \
  acc[1][2] += (w4).y*(h4).z; acc[1][3] += (w4).y*(h4).w;                      \
  acc[2][0] += (w4).z*(h4).x; acc[2][1] += (w4).z*(h4).y;                      \
  acc[2][2] += (w4).z*(h4).z; acc[2][3] += (w4).z*(h4).w;                      \
  acc[3][0] += (w4).w*(h4).x; acc[3][1] += (w4).w*(h4).y;                      \
  acc[3][2] += (w4).w*(h4).z; acc[3][3] += (w4).w*(h4).w;

__global__ __launch_bounds__(THREADS, 2) void lstm_fused(
    const float* __restrict__ input,
    const float* __restrict__ W_ih1, const float* __restrict__ W_hh1,
    const float* __restrict__ b_ih1, const float* __restrict__ b_hh1,
    const float* __restrict__ W_ih2, const float* __restrict__ W_hh2,
    const float* __restrict__ b_ih2, const float* __restrict__ b_hh2,
    float* __restrict__ out)
{
  extern __shared__ float smem[];
  float* w_lds  = smem;                         // [KS][CELL*4]  k*400 + j*4 + g
  float* h_lds  = w_lds + WLDS_FLOATS;          // [CELL][HROW]  (use first BPB cols)
  float* c_lds  = h_lds + CELL * HROW;          // [BPB][CELL]
  float* w2_lds = c_lds + BPB * CELL;           // [4][CELL]
  float* x_lds  = w2_lds + 4 * CELL;            // [BPB]
  float* h2_lds = x_lds + BPB;                  // [BPB]

  const int tid   = threadIdx.x;
  const int jj    = tid & 127;                  // cell index (active < 100)
  const int bb    = tid >> 7;                   // batch group 0..3
  const int bbase = blockIdx.x * BPB;

  // ---------------- one-time staging ----------------
  for (int e = tid; e < WLDS_FLOATS; e += THREADS) {
    int k = e / 400;
    int r = e - k * 400;
    int j = r >> 2, g = r & 3;
    w_lds[e] = W_hh1[(g * CELL + j) * CELL + k];
  }
  for (int e = tid; e < CELL * HROW; e += THREADS) h_lds[e] = 0.f;
  for (int e = tid; e < 4 * CELL; e += THREADS)  w2_lds[e] = W_ih2[e];
  if (tid < BPB) { x_lds[tid] = input[bbase + tid]; h2_lds[tid] = 0.f; }

  float wx[4], bias[4];
  float4 wreg[KR];
  #pragma unroll
  for (int g = 0; g < 4; ++g) { wx[g] = 0.f; bias[g] = 0.f; }
  #pragma unroll
  for (int kk = 0; kk < KR; ++kk) wreg[kk] = make_float4(0.f, 0.f, 0.f, 0.f);

  if (jj < CELL) {
    #pragma unroll
    for (int g = 0; g < 4; ++g) {
      wx[g]   = W_ih1[g * CELL + jj];
      bias[g] = b_ih1[g * CELL + jj] + b_hh1[g * CELL + jj];
    }
    #pragma unroll
    for (int kk = 0; kk < KR; ++kk) {
      wreg[kk].x = W_hh1[(0 * CELL + jj) * CELL + KS + kk];
      wreg[kk].y = W_hh1[(1 * CELL + jj) * CELL + KS + kk];
      wreg[kk].z = W_hh1[(2 * CELL + jj) * CELL + KS + kk];
      wreg[kk].w = W_hh1[(3 * CELL + jj) * CELL + KS + kk];
    }
  }
  float bias2 = 0.f, whh2 = 0.f;
  if (tid < 64) {
    int g2 = tid >> 4;
    bias2 = b_ih2[g2] + b_hh2[g2];
    whh2  = W_hh2[g2];
  }

  float c1[NB] = {0.f, 0.f, 0.f, 0.f};
  float c2 = 0.f;
  __syncthreads();

  const float4* wp = reinterpret_cast<const float4*>(w_lds) + jj;  // +k*CELL
  const float4* hp = reinterpret_cast<const float4*>(h_lds) + bb;  // +k*(HROW/4)

  for (int t = 0; t < TT + FUTS; ++t) {
    // x for my 4 batches (written at end of previous step)
    float4 xv = *reinterpret_cast<const float4*>(&x_lds[4 * bb]);
    float xa[NB] = {xv.x, xv.y, xv.z, xv.w};

    float acc[4][NB];
    #pragma unroll
    for (int g = 0; g < 4; ++g)
      #pragma unroll
      for (int i = 0; i < NB; ++i)
        acc[g][i] = bias[g] + wx[g] * xa[i];

    // prefetch next observed input (latency hidden under the k-loop)
    float xnext = 0.f;
    if (tid < BPB && (t + 1) < TT) xnext = input[(t + 1) * BATCH + bbase + tid];

    // ---- main dot: gates += W_hh1 * h1 ----
    #pragma unroll 4
    for (int k = 0; k < KS; ++k) {
      float4 w4 = wp[k * CELL];        // 4 gate weights for cell jj (b128, conflict-free)
      float4 h4 = hp[k * (HROW / 4)];  // h for my 4 batches (wave-uniform broadcast)
      FMA16(w4, h4);
    }
    #pragma unroll
    for (int kk = 0; kk < KR; ++kk) {  // register tail k = KS..CELL-1
      float4 h4 = hp[(KS + kk) * (HROW / 4)];
      FMA16(wreg[kk], h4);
    }

    // ---- LSTM1 activations ----
    float hn[NB];
    #pragma unroll
    for (int i = 0; i < NB; ++i) {
      float ig = sigf(acc[0][i]);
      float fg = sigf(acc[1][i]);
      float gg = tanhfast(acc[2][i]);
      float og = sigf(acc[3][i]);
      float cn = fg * c1[i] + ig * gg;
      c1[i] = cn;
      hn[i] = og * tanhfast(cn);
    }

    __syncthreads();   // all k-loop reads of h_lds done
    if (jj < CELL) {
      float4 hv; hv.x = hn[0]; hv.y = hn[1]; hv.z = hn[2]; hv.w = hn[3];
      *reinterpret_cast<float4*>(&h_lds[jj * HROW + 4 * bb]) = hv;
      c_lds[(4 * bb + 0) * CELL + jj] = c1[0];
      c_lds[(4 * bb + 1) * CELL + jj] = c1[1];
      c_lds[(4 * bb + 2) * CELL + jj] = c1[2];
      c_lds[(4 * bb + 3) * CELL + jj] = c1[3];
    }
    __syncthreads();   // h/c visible

    // ---- LSTM2 (input = c1, hidden size 1) on wave 0 ----
    if (tid < 64) {
      const int b = tid & 15, g2 = tid >> 4;   // lane = g2*16 + b
      float a = bias2 + whh2 * h2_lds[b];
      const float4* cp  = reinterpret_cast<const float4*>(&c_lds[b * CELL]);
      const float4* w2p = reinterpret_cast<const float4*>(&w2_lds[g2 * CELL]);
      #pragma unroll 5
      for (int q = 0; q < 25; ++q) {
        float4 cv = cp[q]; float4 wv = w2p[q];
        a += wv.x * cv.x + wv.y * cv.y + wv.z * cv.z + wv.w * cv.w;
      }
      float af = __shfl(a, 16 + b);
      float ag = __shfl(a, 32 + b);
      float ao = __shfl(a, 48 + b);
      if (g2 == 0) {
        float i2  = sigf(a);
        float f2  = sigf(af);
        float gg2 = tanhfast(ag);
        float o2  = sigf(ao);
        c2 = f2 * c2 + i2 * gg2;
        float h2n = o2 * tanhfast(c2);
        h2_lds[b] = h2n;
        if (t >= TT) out[(bbase + b) * FUTS + (t - TT)] = c2;
        // next step's lstm1 input: observed x, or fed-back c2
        x_lds[b] = ((t + 1) < TT) ? xnext : c2;
      }
    }
    __syncthreads();
  }
}

extern "C" void kernel_launch(void* const* d_in, const int* in_sizes, int n_in,
                              void* d_out, int out_size, void* d_ws, size_t ws_size,
                              hipStream_t stream) {
  const float* input = (const float*)d_in[0];
  const float* W_ih1 = (const float*)d_in[1];
  const float* W_hh1 = (const float*)d_in[2];
  const float* b_ih1 = (const float*)d_in[3];
  const float* b_hh1 = (const float*)d_in[4];
  const float* W_ih2 = (const float*)d_in[5];
  const float* W_hh2 = (const float*)d_in[6];
  const float* b_ih2 = (const float*)d_in[7];
  const float* b_hh2 = (const float*)d_in[8];
  float* out = (float*)d_out;

  // allow >64KB dynamic LDS (gfx950 has 160 KiB/CU); idempotent, capture-safe
  (void)hipFuncSetAttribute((const void*)lstm_fused,
                            hipFuncAttributeMaxDynamicSharedMemorySize, SMEM_BYTES);

  lstm_fused<<<dim3(BLOCKS), dim3(THREADS), SMEM_BYTES, stream>>>(
      input, W_ih1, W_hh1, b_ih1, b_hh1, W_ih2, W_hh2, b_ih2, b_hh2, out);
}

// Round 2
// 1788.860 us; speedup vs baseline: 2.4901x; 2.4901x over previous
//
#include <hip/hip_runtime.h>

// TsRnn round 2: per-step gates = W_hh1 @ h1 done with bf16 hi/lo MFMA
// (3-product fp32 emulation). 256 blocks x 512 threads (8 waves); block owns
// 16 batch elements, runs all 576 steps. W row-permuted to R=4*cell+gate so
// C-fragment regs hold the 4 gates of one (cell,batch) -> in-register
// activations. A-fragments register-resident. LSTM2 on wave 7 (VALU).

#define TT      512
#define BATCH   4096
#define CELLN   100
#define FUTS    64
#define THREADS 512
#define BPB     16
#define HPITCH  136   // bf16 elems per h-plane row (272 B, 2-way conflicts only)
#define CPITCH  108   // f32 per c-plane row (432 B)
#define W2PITCH 104

typedef __attribute__((ext_vector_type(8))) short bf16x8;
typedef __attribute__((ext_vector_type(4))) float f32x4;

__device__ __forceinline__ unsigned short f2bf(float f) {
  unsigned u = __builtin_bit_cast(unsigned, f);
  unsigned r = (u + 0x7FFFu + ((u >> 16) & 1u)) >> 16;
  return (unsigned short)r;
}
__device__ __forceinline__ float bf2f(unsigned short b) {
  unsigned u = ((unsigned)b) << 16;
  return __builtin_bit_cast(float, u);
}
__device__ __forceinline__ float sigf(float x) {
  return __fdividef(1.f, 1.f + __expf(-x));   // safe at +-inf
}
__device__ __forceinline__ float tanhfast(float x) {
  return 1.f - __fdividef(2.f, __expf(2.f * x) + 1.f);
}

__global__ __launch_bounds__(THREADS, 2) void lstm_mfma(
    const float* __restrict__ input,
    const float* __restrict__ W_ih1, const float* __restrict__ W_hh1,
    const float* __restrict__ b_ih1, const float* __restrict__ b_hh1,
    const float* __restrict__ W_ih2, const float* __restrict__ W_hh2,
    const float* __restrict__ b_ih2, const float* __restrict__ b_hh2,
    float* __restrict__ out)
{
  __shared__ __align__(16) unsigned short h_hi[16][HPITCH];
  __shared__ __align__(16) unsigned short h_lo[16][HPITCH];
  __shared__ __align__(16) float c_sh[16][CPITCH];
  __shared__ __align__(16) float w2_sh[4][W2PITCH];
  __shared__ float x_sh[BPB];

  const int tid   = threadIdx.x;
  const int lane  = tid & 63;
  const int w     = tid >> 6;                 // wave 0..7
  const int bbase = blockIdx.x * BPB;
  const int ntile = (w == 0) ? 4 : 3;         // tiles m = w + 8*i, real iff m < 25

  // ---------------- one-time staging ----------------
  // A-fragments (register-resident): lane holds A[row=16m+(lane&15)][k=32kk+(lane>>4)*8+e]
  // with permuted row R = 4*cell + gate  ->  W_hh1[(gate*100+cell)*100 + k]
  bf16x8 Ahi[4][4], Alo[4][4];
  float  bias_r[4][4], wx_r[4][4];
  #pragma unroll
  for (int i = 0; i < 4; ++i) {
    const int m  = w + 8 * i;
    const int R  = 16 * m + (lane & 15);
    const int ce = R >> 2, g = R & 3;
    #pragma unroll
    for (int kk = 0; kk < 4; ++kk) {
      bf16x8 hi, lo;
      #pragma unroll
      for (int e = 0; e < 8; ++e) {
        float v = 0.f;
        if (m < 25 && ce < CELLN) {
          int k = 32 * kk + (lane >> 4) * 8 + e;
          if (k < CELLN) v = W_hh1[(g * CELLN + ce) * CELLN + k];
        }
        unsigned short vh = f2bf(v);
        unsigned short vl = f2bf(v - bf2f(vh));
        hi[e] = (short)vh; lo[e] = (short)vl;
      }
      Ahi[i][kk] = hi; Alo[i][kk] = lo;
    }
    // C-layout cell for this tile: 4m + (lane>>4); reg r = gate r
    const int cc = 4 * m + (lane >> 4);
    #pragma unroll
    for (int r = 0; r < 4; ++r) {
      if (m < 25 && cc < CELLN) {
        bias_r[i][r] = b_ih1[r * CELLN + cc] + b_hh1[r * CELLN + cc];
        wx_r[i][r]   = W_ih1[r * CELLN + cc];
      } else { bias_r[i][r] = 0.f; wx_r[i][r] = 0.f; }
    }
  }

  for (int e = tid; e < 16 * HPITCH; e += THREADS) {
    (&h_hi[0][0])[e] = 0; (&h_lo[0][0])[e] = 0;
  }
  for (int e = tid; e < 16 * CPITCH; e += THREADS) (&c_sh[0][0])[e] = 0.f;
  for (int e = tid; e < 4 * W2PITCH; e += THREADS) {
    int g = e / W2PITCH, k = e - g * W2PITCH;
    (&w2_sh[0][0])[e] = (k < CELLN) ? W_ih2[g * CELLN + k] : 0.f;
  }
  if (tid < BPB) x_sh[tid] = input[bbase + tid];

  float bias2 = 0.f, whh2 = 0.f;
  if (w == 7) {
    int g2 = lane >> 4;
    bias2 = b_ih2[g2] + b_hh2[g2];
    whh2  = W_hh2[g2];
  }

  float c1[4] = {0.f, 0.f, 0.f, 0.f};
  float c2 = 0.f, h2 = 0.f;                  // wave7 lanes 0..15 own batch b

  bf16x8 Bhi[4], Blo[4];
  #pragma unroll
  for (int kk = 0; kk < 4; ++kk) {
    #pragma unroll
    for (int e = 0; e < 8; ++e) { Bhi[kk][e] = 0; Blo[kk][e] = 0; }
  }
  __syncthreads();

  // ---------------- time loop ----------------
  for (int t = 0; t < TT + FUTS; ++t) {
    // (1) C-init: gates = bias + W_ih1 * x   (x broadcast per batch)
    const float x = x_sh[lane & 15];
    f32x4 acc[4];
    #pragma unroll
    for (int i = 0; i < 4; ++i) {
      #pragma unroll
      for (int r = 0; r < 4; ++r) acc[i][r] = bias_r[i][r] + wx_r[i][r] * x;
    }

    // wave7: prefetch next observed input (consumed at end of step)
    float xnext = 0.f;
    if (w == 7 && lane < BPB && (t + 1) < TT)
      xnext = input[(t + 1) * BATCH + bbase + lane];

    // (2) MFMA: 3-product bf16 emulation of fp32 W_hh1 @ h
    #pragma unroll
    for (int kk = 0; kk < 4; ++kk) {
      #pragma unroll
      for (int i = 0; i < 4; ++i) {
        if (i < 3 || w == 0) {
          acc[i] = __builtin_amdgcn_mfma_f32_16x16x32_bf16(Ahi[i][kk], Bhi[kk], acc[i], 0, 0, 0);
          acc[i] = __builtin_amdgcn_mfma_f32_16x16x32_bf16(Alo[i][kk], Bhi[kk], acc[i], 0, 0, 0);
          acc[i] = __builtin_amdgcn_mfma_f32_16x16x32_bf16(Ahi[i][kk], Blo[kk], acc[i], 0, 0, 0);
        }
      }
    }

    // (3) activations fully in-register (regs = 4 gates of one (cell,batch))
    float hnew[4];
    #pragma unroll
    for (int i = 0; i < 4; ++i) {
      if (i < ntile) {
        float ig = sigf(acc[i][0]);
        float fg = sigf(acc[i][1]);
        float gg = tanhfast(acc[i][2]);
        float og = sigf(acc[i][3]);
        float cn = fg * c1[i] + ig * gg;
        c1[i]   = cn;
        hnew[i] = og * tanhfast(cn);
      }
    }

    // (4) publish h (bf16 hi/lo planes) and c (fp32 plane for lstm2)
    #pragma unroll
    for (int i = 0; i < 4; ++i) {
      const int m  = w + 8 * i;
      const int cc = 4 * m + (lane >> 4);
      if (m < 25) {                    // cc <= 99 guaranteed when m < 25
        const int b = lane & 15;
        float hv = hnew[i];
        unsigned short hh = f2bf(hv);
        unsigned short hl = f2bf(hv - bf2f(hh));
        h_hi[b][cc] = hh;
        h_lo[b][cc] = hl;
        c_sh[b][cc] = c1[i];
      }
    }
    __syncthreads();                                   // b2: h,c published

    // (6a) B-build for next step: lane reads h[b][8 consecutive k]
    {
      const int b    = lane & 15;
      const int koff = (lane >> 4) * 8;
      #pragma unroll
      for (int kk = 0; kk < 4; ++kk) {
        Bhi[kk] = *(const bf16x8*)&h_hi[b][kk * 32 + koff];
        Blo[kk] = *(const bf16x8*)&h_lo[b][kk * 32 + koff];
      }
    }

    // (6b) LSTM2 on wave 7 (input = c1, hidden size 1), overlapped with B-build
    if (w == 7) {
      const int b = lane & 15, g2 = lane >> 4;
      float h2b = __shfl(h2, b);                       // h2 of batch b (lane b)
      float a = bias2 + whh2 * h2b;
      const f32x4* cp  = (const f32x4*)&c_sh[b][0];
      const f32x4* wp2 = (const f32x4*)&w2_sh[g2][0];
      #pragma unroll 5
      for (int q = 0; q < 25; ++q) {
        f32x4 cv = cp[q], wv = wp2[q];
        a += wv[0] * cv[0] + wv[1] * cv[1] + wv[2] * cv[2] + wv[3] * cv[3];
      }
      float af = __shfl(a, 16 + b);
      float ag = __shfl(a, 32 + b);
      float ao = __shfl(a, 48 + b);
      if (g2 == 0) {
        float i2  = sigf(a);
        float f2  = sigf(af);
        float gg2 = tanhfast(ag);
        float o2  = sigf(ao);
        c2 = f2 * c2 + i2 * gg2;
        h2 = o2 * tanhfast(c2);
        if (t >= TT) out[(bbase + b) * FUTS + (t - TT)] = c2;
        x_sh[b] = ((t + 1) < TT) ? xnext : c2;         // next lstm1 input
      }
    }
    __syncthreads();                                   // b3: B built, x ready
  }
}

extern "C" void kernel_launch(void* const* d_in, const int* in_sizes, int n_in,
                              void* d_out, int out_size, void* d_ws, size_t ws_size,
                              hipStream_t stream) {
  const float* input = (const float*)d_in[0];
  const float* W_ih1 = (const float*)d_in[1];
  const float* W_hh1 = (const float*)d_in[2];
  const float* b_ih1 = (const float*)d_in[3];
  const float* b_hh1 = (const float*)d_in[4];
  const float* W_ih2 = (const float*)d_in[5];
  const float* W_hh2 = (const float*)d_in[6];
  const float* b_ih2 = (const float*)d_in[7];
  const float* b_hh2 = (const float*)d_in[8];
  float* out = (float*)d_out;

  lstm_mfma<<<dim3(BATCH / BPB), dim3(THREADS), 0, stream>>>(
      input, W_ih1, W_hh1, b_ih1, b_hh1, W_ih2, W_hh2, b_ih2, b_hh2, out);
}

// Round 3
// 1112.041 us; speedup vs baseline: 4.0057x; 1.6086x over previous
//
#include <hip/hip_runtime.h>

// TsRnn round 3: critical-path collapse.
//  - LSTM2 pipelined one step behind (wave 7) during the observed phase;
//    h/c LDS planes double-buffered by step parity.
//  - ONE barrier per observed step (two only during the 64 future steps).
//  - Tile balance {4,4,4,3,3,3,3,1}: wave 7 carries LSTM2 instead of tiles.
//  - exp2-scaled gates: log2e folded into weights/biases at staging.
//  - Split accumulators (hi*hi vs cross terms) to shorten MFMA dep chains.

#define TT      512
#define BATCH   4096
#define CELLN   100
#define FUTS    64
#define THREADS 512
#define BPB     16
#define HPITCH  136   // bf16 elems per h-plane row (272 B, 16B-aligned rows)
#define CPITCH  108   // f32 per c-plane row
#define W2PITCH 104
#define LOG2E   1.4426950408889634f

typedef __attribute__((ext_vector_type(8))) short bf16x8;
typedef __attribute__((ext_vector_type(4))) float f32x4;

__device__ __forceinline__ unsigned short f2bf(float f) {
  unsigned u = __builtin_bit_cast(unsigned, f);
  unsigned r = (u + 0x7FFFu + ((u >> 16) & 1u)) >> 16;
  return (unsigned short)r;
}
__device__ __forceinline__ float bf2f(unsigned short b) {
  return __builtin_bit_cast(float, ((unsigned)b) << 16);
}
// input s = x*log2e -> sigmoid(x) = 1/(1+2^-s)
__device__ __forceinline__ float sig_s(float s) {
  return __builtin_amdgcn_rcpf(1.f + __builtin_amdgcn_exp2f(-s));
}
// input u = 2*log2e*x -> tanh(x) = 1 - 2/(2^u+1)
__device__ __forceinline__ float tanh_s(float u) {
  return fmaf(-2.f, __builtin_amdgcn_rcpf(__builtin_amdgcn_exp2f(u) + 1.f), 1.f);
}

template <int NT>
__device__ __forceinline__ void tiles_step(
    const bf16x8 (&Ahi)[4][4], const bf16x8 (&Alo)[4][4],
    const bf16x8 (&Bhi)[4], const bf16x8 (&Blo)[4],
    const float (&bias_r)[4][4], const float (&wx_r)[4][4],
    float (&c1)[4], float xreg, int mstart, int lane,
    unsigned short (*h_hi)[HPITCH], unsigned short (*h_lo)[HPITCH],
    float (*c_sh)[CPITCH])
{
  f32x4 accA[NT], accB[NT];
  #pragma unroll
  for (int i = 0; i < NT; ++i) {
    #pragma unroll
    for (int r = 0; r < 4; ++r) {
      accA[i][r] = fmaf(wx_r[i][r], xreg, bias_r[i][r]);
      accB[i][r] = 0.f;
    }
  }
  #pragma unroll
  for (int kk = 0; kk < 4; ++kk)
    #pragma unroll
    for (int i = 0; i < NT; ++i)
      accA[i] = __builtin_amdgcn_mfma_f32_16x16x32_bf16(Ahi[i][kk], Bhi[kk], accA[i], 0, 0, 0);
  #pragma unroll
  for (int kk = 0; kk < 4; ++kk)
    #pragma unroll
    for (int i = 0; i < NT; ++i)
      accB[i] = __builtin_amdgcn_mfma_f32_16x16x32_bf16(Alo[i][kk], Bhi[kk], accB[i], 0, 0, 0);
  #pragma unroll
  for (int kk = 0; kk < 4; ++kk)
    #pragma unroll
    for (int i = 0; i < NT; ++i)
      accB[i] = __builtin_amdgcn_mfma_f32_16x16x32_bf16(Ahi[i][kk], Blo[kk], accB[i], 0, 0, 0);

  const int b = lane & 15;
  #pragma unroll
  for (int i = 0; i < NT; ++i) {
    float si = accA[i][0] + accB[i][0];
    float sf = accA[i][1] + accB[i][1];
    float sg = accA[i][2] + accB[i][2];
    float so = accA[i][3] + accB[i][3];
    float ig = sig_s(si), fg = sig_s(sf), gg = tanh_s(sg), og = sig_s(so);
    float cn = fmaf(fg, c1[i], ig * gg);
    c1[i] = cn;
    float hn = og * tanh_s(2.f * LOG2E * cn);
    const int cc = 4 * (mstart + i) + (lane >> 4);
    unsigned short hh = f2bf(hn);
    unsigned short hl = f2bf(hn - bf2f(hh));
    h_hi[b][cc] = hh;
    h_lo[b][cc] = hl;
    c_sh[b][cc] = cn;
  }
}

__global__ __launch_bounds__(THREADS, 2) void lstm_mfma3(
    const float* __restrict__ input,
    const float* __restrict__ W_ih1, const float* __restrict__ W_hh1,
    const float* __restrict__ b_ih1, const float* __restrict__ b_hh1,
    const float* __restrict__ W_ih2, const float* __restrict__ W_hh2,
    const float* __restrict__ b_ih2, const float* __restrict__ b_hh2,
    float* __restrict__ out)
{
  __shared__ __align__(16) unsigned short h_hi[2][BPB][HPITCH];
  __shared__ __align__(16) unsigned short h_lo[2][BPB][HPITCH];
  __shared__ __align__(16) float c_sh[2][BPB][CPITCH];
  __shared__ __align__(16) float w2_sh[4][W2PITCH];
  __shared__ float x2_sh[BPB];

  const int tid   = threadIdx.x;
  const int lane  = tid & 63;
  const int w     = tid >> 6;                       // wave 0..7
  const int bbase = blockIdx.x * BPB;
  // tile balance: waves 0-2 -> 4 tiles, 3-6 -> 3, wave 7 -> 1 (+ LSTM2)
  const int cnt    = (w < 3) ? 4 : ((w == 7) ? 1 : 3);
  const int mstart = (w < 3) ? 4 * w : ((w == 7) ? 24 : 12 + 3 * (w - 3));

  // ---- A-fragments + bias/wx (exp2-scaled), register-resident ----
  bf16x8 Ahi[4][4], Alo[4][4];
  float  bias_r[4][4], wx_r[4][4];
  #pragma unroll
  for (int i = 0; i < 4; ++i) {
    #pragma unroll
    for (int kk = 0; kk < 4; ++kk)
      #pragma unroll
      for (int e = 0; e < 8; ++e) { Ahi[i][kk][e] = 0; Alo[i][kk][e] = 0; }
    #pragma unroll
    for (int r = 0; r < 4; ++r) { bias_r[i][r] = 0.f; wx_r[i][r] = 0.f; }
    if (i < cnt) {
      const int m  = mstart + i;
      const int R  = 16 * m + (lane & 15);
      const int ce = R >> 2, g = R & 3;
      const float sc = (g == 2) ? 2.f * LOG2E : LOG2E;
      #pragma unroll
      for (int kk = 0; kk < 4; ++kk) {
        #pragma unroll
        for (int e = 0; e < 8; ++e) {
          int k = 32 * kk + (lane >> 4) * 8 + e;
          float v = (k < CELLN) ? W_hh1[(g * CELLN + ce) * CELLN + k] * sc : 0.f;
          unsigned short vh = f2bf(v);
          Ahi[i][kk][e] = (short)vh;
          Alo[i][kk][e] = (short)f2bf(v - bf2f(vh));
        }
      }
      const int cc = 4 * m + (lane >> 4);
      #pragma unroll
      for (int r = 0; r < 4; ++r) {
        const float scr = (r == 2) ? 2.f * LOG2E : LOG2E;
        bias_r[i][r] = (b_ih1[r * CELLN + cc] + b_hh1[r * CELLN + cc]) * scr;
        wx_r[i][r]   = W_ih1[r * CELLN + cc] * scr;
      }
    }
  }

  for (int e = tid; e < 4 * W2PITCH; e += THREADS) {
    int g = e / W2PITCH, k = e - g * W2PITCH;
    float sc = (g == 2) ? 2.f * LOG2E : LOG2E;
    (&w2_sh[0][0])[e] = (k < CELLN) ? W_ih2[g * CELLN + k] * sc : 0.f;
  }
  float bias2 = 0.f, whh2 = 0.f;
  if (w == 7) {
    int g2 = lane >> 4;
    float sc = (g2 == 2) ? 2.f * LOG2E : LOG2E;
    bias2 = (b_ih2[g2] + b_hh2[g2]) * sc;
    whh2  = W_hh2[g2] * sc;
  }

  float c1[4] = {0.f, 0.f, 0.f, 0.f};
  float c2 = 0.f, h2 = 0.f;                   // wave7, lanes 0..15 own batch b
  bf16x8 Bhi[4], Blo[4];
  #pragma unroll
  for (int kk = 0; kk < 4; ++kk)
    #pragma unroll
    for (int e = 0; e < 8; ++e) { Bhi[kk][e] = 0; Blo[kk][e] = 0; }

  float xreg = input[bbase + (lane & 15)];
  __syncthreads();                            // w2 staged

  for (int t = 0; t < TT + FUTS; ++t) {
    const int p = t & 1;
    // prefetch next observed input early (hidden under MFMA+act)
    float xnext = 0.f;
    if (t + 1 < TT) xnext = input[(t + 1) * BATCH + bbase + (lane & 15)];

    if (cnt == 4)
      tiles_step<4>(Ahi, Alo, Bhi, Blo, bias_r, wx_r, c1, xreg, mstart, lane,
                    h_hi[p], h_lo[p], c_sh[p]);
    else if (cnt == 3)
      tiles_step<3>(Ahi, Alo, Bhi, Blo, bias_r, wx_r, c1, xreg, mstart, lane,
                    h_hi[p], h_lo[p], c_sh[p]);
    else
      tiles_step<1>(Ahi, Alo, Bhi, Blo, bias_r, wx_r, c1, xreg, mstart, lane,
                    h_hi[p], h_lo[p], c_sh[p]);

    __syncthreads();                          // h/c(t) published (parity p)

    // B-build for step t+1 (reads parity p; publish(t+1) writes p^1)
    {
      const int b    = lane & 15;
      const int koff = (lane >> 4) * 8;
      #pragma unroll
      for (int kk = 0; kk < 4; ++kk) {
        Bhi[kk] = *(const bf16x8*)&h_hi[p][b][kk * 32 + koff];
        Blo[kk] = *(const bf16x8*)&h_lo[p][b][kk * 32 + koff];
      }
    }

    // LSTM2(t) on wave 7 — off the critical path during observed phase
    if (w == 7) {
      const int b = lane & 15, g2 = lane >> 4;
      float h2b = __shfl(h2, b);
      float a = fmaf(whh2, h2b, bias2);
      const f32x4* cp  = (const f32x4*)&c_sh[p][b][0];
      const f32x4* wp2 = (const f32x4*)&w2_sh[g2][0];
      #pragma unroll 5
      for (int q = 0; q < 25; ++q) {
        f32x4 cv = cp[q], wv = wp2[q];
        a += wv[0] * cv[0] + wv[1] * cv[1] + wv[2] * cv[2] + wv[3] * cv[3];
      }
      float af = __shfl(a, 16 + b);
      float ag = __shfl(a, 32 + b);
      float ao = __shfl(a, 48 + b);
      if (g2 == 0) {
        float i2  = sig_s(a);
        float f2  = sig_s(af);
        float gg2 = tanh_s(ag);
        float o2  = sig_s(ao);
        c2 = fmaf(f2, c2, i2 * gg2);
        h2 = o2 * tanh_s(2.f * LOG2E * c2);
        if (t >= TT) out[(bbase + b) * FUTS + (t - TT)] = c2;
        if (t >= TT - 1) x2_sh[b] = c2;       // next lstm1 input (future phase)
      }
    }

    if (t >= TT - 1) {
      if (t < TT + FUTS - 1) {
        __syncthreads();                      // wait for wave7's c2 -> x
        xreg = x2_sh[lane & 15];
      }
    } else {
      xreg = xnext;
    }
  }
}

extern "C" void kernel_launch(void* const* d_in, const int* in_sizes, int n_in,
                              void* d_out, int out_size, void* d_ws, size_t ws_size,
                              hipStream_t stream) {
  const float* input = (const float*)d_in[0];
  const float* W_ih1 = (const float*)d_in[1];
  const float* W_hh1 = (const float*)d_in[2];
  const float* b_ih1 = (const float*)d_in[3];
  const float* b_hh1 = (const float*)d_in[4];
  const float* W_ih2 = (const float*)d_in[5];
  const float* W_hh2 = (const float*)d_in[6];
  const float* b_ih2 = (const float*)d_in[7];
  const float* b_hh2 = (const float*)d_in[8];
  float* out = (float*)d_out;

  lstm_mfma3<<<dim3(BATCH / BPB), dim3(THREADS), 0, stream>>>(
      input, W_ih1, W_hh1, b_ih1, b_hh1, W_ih2, W_hh2, b_ih2, b_hh2, out);
}